// Round 15
// baseline (274.703 us; speedup 1.0000x reference)
//
#include <hip/hip_runtime.h>
#include <math.h>

#define NROW 1024
#define DIN  128
#define DOUT 256
#define MEMN 65536
#define QTHB  4286377472u   // full-bits threshold (== (bits>>9) >= 8371831)
#define RCAP  768

typedef __attribute__((ext_vector_type(8))) short bf16x8;
typedef __attribute__((ext_vector_type(4))) float f32x4;
typedef __attribute__((ext_vector_type(8))) unsigned short u16x8;

// ---------------- static device scratch ------------------------------------
__device__ unsigned short g_fnb[NROW * DOUT];
__device__ unsigned short g_bank2b[(size_t)MEMN * DOUT];
__device__ unsigned short g_pairsb[(size_t)NROW * MEMN];     // 128 MB bf16
__device__ int            g_owner[MEMN];
__device__ unsigned short g_meta[MEMN];                      // label+1 if flag2>0 else 0
__device__ float          g_clssum[156];
__device__ float          g_posv[NROW * 1024];               // per-row positive values (f32)
__device__ int            g_pcnt[NROW];
__device__ float          g_negv[NROW * 512];                // per-row neg values >= floor
__device__ int            g_ncnt[NROW];
__device__ uint2          g_cand[NROW * RCAP];               // rand candidates (q, col)
__device__ int            g_rcnt[NROW];
__device__ float          g_pos[NROW * 8];
__device__ float          g_neg[NROW * 32];
__device__ float          g_rnd[NROW * 32];

__device__ __forceinline__ unsigned short f2bf(float x) {
  union { float f; unsigned u; } c; c.f = x;
  unsigned r = c.u + 0x7fffu + ((c.u >> 16) & 1u);
  return (unsigned short)(r >> 16);
}
__device__ __forceinline__ float bf2f(unsigned short b) {
  return __uint_as_float((unsigned)b << 16);
}
__device__ __forceinline__ float bflo(unsigned u) { return __uint_as_float(u << 16); }
__device__ __forceinline__ float bfhi(unsigned u) { return __uint_as_float(u & 0xffff0000u); }

// ---------------- threefry2x32 key=(0,1) -----------------------------------
#define ROTL(x, r) (((x) << (r)) | ((x) >> (32 - (r))))
#define TF_R2(r) { a0 += a1; a1 = ROTL(a1, r); a1 ^= a0; \
                   b0 += b1; b1 = ROTL(b1, r); b1 ^= b0; }
__device__ __forceinline__ void tf2(unsigned &a0, unsigned &a1, unsigned &b0, unsigned &b1) {
  const unsigned ks1 = 1u, ks2 = 0x1BD11BDBu;
  a1 += ks1; b1 += ks1;
  TF_R2(13) TF_R2(15) TF_R2(26) TF_R2(6)
  a0 += ks1; a1 += ks2 + 1u; b0 += ks1; b1 += ks2 + 1u;
  TF_R2(17) TF_R2(29) TF_R2(16) TF_R2(24)
  a0 += ks2; a1 += 2u;       b0 += ks2; b1 += 2u;
  TF_R2(13) TF_R2(15) TF_R2(26) TF_R2(6)
  a1 += ks1 + 3u;            b1 += ks1 + 3u;
  TF_R2(17) TF_R2(29) TF_R2(16) TF_R2(24)
  a0 += ks1; a1 += ks2 + 4u; b0 += ks1; b1 += ks2 + 4u;
  TF_R2(13) TF_R2(15) TF_R2(26) TF_R2(6)
  a0 += ks2; a1 += 5u;       b0 += ks2; b1 += 5u;
}
__device__ __forceinline__ void tfround(unsigned &x0, unsigned &x1, int r) {
  x0 += x1; x1 = ROTL(x1, r); x1 ^= x0;
}
__device__ __forceinline__ unsigned threefry_out(unsigned x0, unsigned x1, bool hi) {
  const unsigned ks1 = 1u, ks2 = 0x1BD11BDBu;
  x1 += ks1;
  tfround(x0,x1,13); tfround(x0,x1,15); tfround(x0,x1,26); tfround(x0,x1,6);
  x0 += ks1; x1 += ks2 + 1u;
  tfround(x0,x1,17); tfround(x0,x1,29); tfround(x0,x1,16); tfround(x0,x1,24);
  x0 += ks2; x1 += 2u;
  tfround(x0,x1,13); tfround(x0,x1,15); tfround(x0,x1,26); tfround(x0,x1,6);
  x1 += ks1 + 3u;
  tfround(x0,x1,17); tfround(x0,x1,29); tfround(x0,x1,16); tfround(x0,x1,24);
  x0 += ks1; x1 += ks2 + 4u;
  tfround(x0,x1,13); tfround(x0,x1,15); tfround(x0,x1,26); tfround(x0,x1,6);
  x0 += ks2; x1 += 5u;
  return hi ? x1 : x0;
}

// ---------------- prep kernels ----------------------------------------------
__global__ void k_owner_init() {
  int j = blockIdx.x * 256 + threadIdx.x;
  g_owner[j] = -1;
  if (j < 156) g_clssum[j] = 0.0f;
  if (j < NROW) { g_rcnt[j] = 0; g_pcnt[j] = 0; g_ncnt[j] = 0; }
}
__global__ void k_owner_scatter(const long long* idx) {
  int i = blockIdx.x * 256 + threadIdx.x;
  if (i < NROW) atomicMax(&g_owner[(int)idx[i]], i);
}
__global__ void k_meta(const float* bank_flag, const int* label_all) {
  __shared__ float s_cls[156];
  int t = threadIdx.x;
  int j = blockIdx.x * 256 + t;
  if (t < 156) s_cls[t] = 0.0f;
  __syncthreads();
  float fl = (g_owner[j] >= 0) ? 1.0f : bank_flag[j];
  int la = label_all[j];
  unsigned short m = (fl > 0.0f) ? (unsigned short)(la + 1) : (unsigned short)0;
  g_meta[j] = m;
  if (m) { atomicAdd(&s_cls[la], fl); atomicAdd(&s_cls[155], fl); }
  __syncthreads();
  if (t < 156 && s_cls[t] != 0.0f) atomicAdd(&g_clssum[t], s_cls[t]);
}

__global__ __launch_bounds__(256) void k_fn(const float* f, const float* W, const float* b) {
  int i = blockIdx.x, t = threadIdx.x;
  __shared__ __align__(16) float sf[DIN];
  __shared__ float sred[256];
  if (t < DIN / 4) ((float4*)sf)[t] = ((const float4*)(f + (size_t)i * DIN))[t];
  __syncthreads();
  const float4* wrow = (const float4*)(W + (size_t)t * DIN);
  float acc = 0.0f;
  #pragma unroll
  for (int k = 0; k < DIN / 4; ++k) {
    float4 wv = wrow[k]; float4 fv = ((float4*)sf)[k];
    acc = fmaf(wv.x, fv.x, acc); acc = fmaf(wv.y, fv.y, acc);
    acc = fmaf(wv.z, fv.z, acc); acc = fmaf(wv.w, fv.w, acc);
  }
  acc += b[t];
  sred[t] = acc * acc;
  __syncthreads();
  for (int s = 128; s > 0; s >>= 1) { if (t < s) sred[t] += sred[t + s]; __syncthreads(); }
  g_fnb[(size_t)i * DOUT + t] = f2bf(acc * (1.0f / sqrtf(sred[0])));
}

__global__ __launch_bounds__(256) void k_bank2(const float* Bank) {
  int j = blockIdx.x * 4 + (threadIdx.x >> 6);
  int t = threadIdx.x & 63;
  int own = g_owner[j];
  uint2 o;
  if (own >= 0) {
    o = ((const uint2*)(g_fnb + (size_t)own * DOUT))[t];
  } else {
    float4 v = ((const float4*)(Bank + (size_t)j * DOUT))[t];
    o.x = (unsigned)f2bf(v.x) | ((unsigned)f2bf(v.y) << 16);
    o.y = (unsigned)f2bf(v.z) | ((unsigned)f2bf(v.w) << 16);
  }
  ((uint2*)(g_bank2b + (size_t)j * DOUT))[t] = o;
}

// ---------------- fused: GEMM tile + post-epilogue rand slice (R12 form) ----
#define GBK 32
__device__ __forceinline__ void gload16(const void* g, void* l) {
  __builtin_amdgcn_global_load_lds((const __attribute__((address_space(1))) void*)g,
                                   (__attribute__((address_space(3))) void*)l, 16, 0, 0);
}

__global__ __launch_bounds__(256) void k_gemm_rand() {
  __shared__ __align__(16) unsigned short lds[2][2][128 * GBK];
  const int tid = threadIdx.x, lane = tid & 63, w = tid >> 6;
  int bid = blockIdx.x;
  int swz = (bid & 7) * 512 + (bid >> 3);
  const int row0 = (swz & 7) * 128, col0 = (swz >> 3) * 128;
  const int wm = w >> 1, wn = w & 1;

  f32x4 acc[4][4];
  #pragma unroll
  for (int i = 0; i < 4; ++i)
    #pragma unroll
    for (int j = 0; j < 4; ++j) acc[i][j] = (f32x4){0.f, 0.f, 0.f, 0.f};

  int aoff[4], boff[4];
  #pragma unroll
  for (int mf = 0; mf < 4; ++mf) {
    int ra = wm * 64 + mf * 16 + (lane & 15);
    int ca = (lane >> 4) ^ ((ra >> 1) & 3);
    aoff[mf] = ra * GBK + ca * 8;
    int rb = wn * 64 + mf * 16 + (lane & 15);
    int cb2 = (lane >> 4) ^ ((rb >> 1) & 3);
    boff[mf] = rb * GBK + cb2 * 8;
  }

  auto stage = [&](int buf, int kt) {
    #pragma unroll
    for (int q = 0; q < 2; ++q) {
      int g  = w * 2 + q;
      int ci = g * 64 + lane;
      int r  = ci >> 2, c = ci & 3;
      int cs = c ^ ((r >> 1) & 3);
      gload16(g_fnb    + (size_t)(row0 + r) * DOUT + kt + cs * 8, &lds[buf][0][g * 512]);
      gload16(g_bank2b + (size_t)(col0 + r) * DOUT + kt + cs * 8, &lds[buf][1][g * 512]);
    }
  };

  stage(0, 0);
  __syncthreads();
  int cur = 0;
  for (int kt = 0; kt < DOUT; kt += GBK) {
    if (kt + GBK < DOUT) stage(cur ^ 1, kt + GBK);
    bf16x8 af[4], bf_[4];
    #pragma unroll
    for (int mf = 0; mf < 4; ++mf) af[mf]  = *(const bf16x8*)&lds[cur][0][aoff[mf]];
    #pragma unroll
    for (int nf = 0; nf < 4; ++nf) bf_[nf] = *(const bf16x8*)&lds[cur][1][boff[nf]];
    #pragma unroll
    for (int mf = 0; mf < 4; ++mf)
      #pragma unroll
      for (int nf = 0; nf < 4; ++nf)
        acc[mf][nf] = __builtin_amdgcn_mfma_f32_16x16x32_bf16(bf_[nf], af[mf], acc[mf][nf], 0, 0, 0);
    __syncthreads();
    cur ^= 1;
  }

  #pragma unroll
  for (int mf = 0; mf < 4; ++mf) {
    int rg = row0 + wm * 64 + mf * 16 + (lane & 15);
    #pragma unroll
    for (int nf = 0; nf < 4; ++nf) {
      int cg = col0 + wn * 64 + nf * 16 + ((lane >> 4) << 2);
      uint2 o;
      o.x = (unsigned)f2bf(acc[mf][nf][0]) | ((unsigned)f2bf(acc[mf][nf][1]) << 16);
      o.y = (unsigned)f2bf(acc[mf][nf][2]) | ((unsigned)f2bf(acc[mf][nf][3]) << 16);
      *(uint2*)(g_pairsb + (size_t)rg * MEMN + cg) = o;
    }
  }

  // ---- rand phase: slice (rp = bid>>3, sub = bid&7), 8192 j per block -----
  int* s_cnt = (int*)&lds[0][0][0];           // 2 counters
  uint2* s_rbuf = (uint2*)(s_cnt + 4);        // [2][64] candidates
  __syncthreads();                            // staging LDS now dead
  if (tid < 2) s_cnt[tid] = 0;
  __syncthreads();
  const int rp = bid >> 3, sub = bid & 7;
  const unsigned rbase = (unsigned)rp << 16;
  const int j0 = sub * 8192 + tid;
  #pragma unroll 2
  for (int it = 0; it < 16; ++it) {
    const int jA = j0 + it * 256;
    const int jB = jA + 4096;
    unsigned a0 = rbase + (unsigned)jA, a1 = a0 + 0x2000000u;
    unsigned b0 = rbase + (unsigned)jB, b1 = b0 + 0x2000000u;
    tf2(a0, a1, b0, b1);
    if (a0 >= QTHB || a1 >= QTHB || b0 >= QTHB || b1 >= QTHB) {
      if (a0 >= QTHB) { int p = atomicAdd(&s_cnt[0], 1); if (p < 64) s_rbuf[p]      = make_uint2(a0 >> 9, (unsigned)jA); }
      if (a1 >= QTHB) { int p = atomicAdd(&s_cnt[1], 1); if (p < 64) s_rbuf[64 + p] = make_uint2(a1 >> 9, (unsigned)jA); }
      if (b0 >= QTHB) { int p = atomicAdd(&s_cnt[0], 1); if (p < 64) s_rbuf[p]      = make_uint2(b0 >> 9, (unsigned)jB); }
      if (b1 >= QTHB) { int p = atomicAdd(&s_cnt[1], 1); if (p < 64) s_rbuf[64 + p] = make_uint2(b1 >> 9, (unsigned)jB); }
    }
  }
  __syncthreads();
  if (w < 2) {
    int cl = s_cnt[w];
    int row = rp + w * 512;
    int adv = (cl <= 64) ? cl : (RCAP + 1024);    // overflow -> force fallback
    int base_ = 0;
    if (lane == 0) base_ = atomicAdd(&g_rcnt[row], adv);
    base_ = __shfl(base_, 0);
    int n = cl < 64 ? cl : 64;
    if (lane < n) {
      int dst = base_ + lane;
      if (dst < RCAP) g_cand[row * RCAP + dst] = s_rbuf[w * 64 + lane];
    }
  }
}

// ---------------- scan pairs -> per-row pos/neg lists (8 blocks/row) --------
#define SPCAP 160
#define SNCAP 96
__global__ __launch_bounds__(256) void k_scan(const int* label) {
  const int row = blockIdx.x >> 3, s = blockIdx.x & 7;
  const int tid = threadIdx.x;
  __shared__ float s_pb[SPCAP];
  __shared__ float s_nb[SNCAP];
  __shared__ int s_pc, s_nc, s_pbase, s_nbase;
  if (tid == 0) { s_pc = 0; s_nc = 0; }
  __syncthreads();
  const int lab = label[row] + 1;
  const unsigned short* prow = g_pairsb + (size_t)row * MEMN + s * 8192;
  const unsigned short* mrow = g_meta + s * 8192;

  #pragma unroll
  for (int it = 0; it < 4; ++it) {
    int p8 = it * 256 + tid;                       // 0..1023
    u16x8 pb = *(const u16x8*)(prow + p8 * 8);
    u16x8 mb = *(const u16x8*)(mrow + p8 * 8);
    unsigned pm = 0, nm = 0;
    #pragma unroll
    for (int q = 0; q < 8; ++q) {
      int m = mb[q];
      unsigned isp = (unsigned)(m == lab);
      unsigned isn = (unsigned)((m != 0) & (m != lab) & ((short)pb[q] >= (short)0x3E40));
      pm |= isp << q;
      nm |= isn << q;
    }
    while (pm) { int q = __builtin_ctz(pm); pm &= pm - 1; int ix = atomicAdd(&s_pc, 1); if (ix < SPCAP) s_pb[ix] = bf2f(pb[q]); }
    while (nm) { int q = __builtin_ctz(nm); nm &= nm - 1; int ix = atomicAdd(&s_nc, 1); if (ix < SNCAP) s_nb[ix] = bf2f(pb[q]); }
  }
  __syncthreads();
  if (tid == 0) {
    int c = s_pc;
    s_pbase = atomicAdd(&g_pcnt[row], (c <= SPCAP) ? c : 100000);
  } else if (tid == 64) {
    int c = s_nc;
    s_nbase = atomicAdd(&g_ncnt[row], (c <= SNCAP) ? c : 100000);
  }
  __syncthreads();
  int pc = s_pc < SPCAP ? s_pc : SPCAP;
  int nc = s_nc < SNCAP ? s_nc : SNCAP;
  for (int ix = tid; ix < pc; ix += 256) { int d = s_pbase + ix; if (d < 1024) g_posv[row * 1024 + d] = s_pb[ix]; }
  for (int ix = tid; ix < nc; ix += 256) { int d = s_nbase + ix; if (d < 512)  g_negv[row * 512 + d]  = s_nb[ix]; }
}

// ---------------- per-row selection from lists -------------------------------
__global__ __launch_bounds__(192) void k_select(const int* label) {
  const int row = blockIdx.x, tid = threadIdx.x, lane = tid & 63, wid = tid >> 6;
  __shared__ float s_fnf[256];
  for (int i = tid; i < 256; i += 192) s_fnf[i] = bf2f(g_fnb[(size_t)row * DOUT + i]);
  __syncthreads();
  const int lab = label[row] + 1;

  if (wid == 0) {
    // ---- top-32 negatives
    int ncq = g_ncnt[row];
    if (ncq >= 32 && ncq <= 512) {
      float vals[8];
      #pragma unroll
      for (int q = 0; q < 8; ++q) { int ix = q * 64 + lane; vals[q] = ix < ncq ? g_negv[row * 512 + ix] : -3.0e38f; }
      #pragma unroll 1
      for (int r = 0; r < 32; ++r) {
        float bv = vals[0]; int bq = 0;
        #pragma unroll
        for (int q = 1; q < 8; ++q) { bool t = vals[q] > bv; bv = t ? vals[q] : bv; bq = t ? q : bq; }
        int bl = lane;
        #pragma unroll
        for (int off = 32; off; off >>= 1) {
          float ov = __shfl_xor(bv, off); int ol = __shfl_xor(bl, off);
          bool t = ov > bv || (ov == bv && ol < bl);
          bv = t ? ov : bv; bl = t ? ol : bl;
        }
        if (lane == bl) {
          #pragma unroll
          for (int q = 0; q < 8; ++q) vals[q] = (q == bq) ? -3.0e38f : vals[q];
        }
        if (lane == 0) g_neg[row * 32 + r] = bv;
      }
    } else {
      // exact fallback: recompute all dots (never taken on this data)
      float ng[32];
      #pragma unroll
      for (int s = 0; s < 32; ++s) ng[s] = -3.0e38f;
      #pragma unroll 1
      for (int c0 = 0; c0 < 1024; ++c0) {
        int col = c0 * 64 + lane;
        int m = g_meta[col];
        if (m == 0 || m == lab) continue;
        const uint2* br = (const uint2*)(g_bank2b + (size_t)col * DOUT);
        float d = 0.f;
        #pragma unroll 8
        for (int k = 0; k < 64; ++k) {
          uint2 wv = br[k];
          d += s_fnf[k*4+0] * bflo(wv.x) + s_fnf[k*4+1] * bfhi(wv.x)
             + s_fnf[k*4+2] * bflo(wv.y) + s_fnf[k*4+3] * bfhi(wv.y);
        }
        if (d > ng[31]) {
          #pragma unroll
          for (int s = 31; s >= 1; --s) ng[s] = (d > ng[s]) ? ((d > ng[s-1]) ? ng[s-1] : d) : ng[s];
          ng[0] = (d > ng[0]) ? d : ng[0];
        }
      }
      #pragma unroll 1
      for (int r = 0; r < 32; ++r) {
        float bv = ng[0]; int bl = lane;
        #pragma unroll
        for (int off = 32; off; off >>= 1) {
          float ov = __shfl_xor(bv, off); int ol = __shfl_xor(bl, off);
          bool t = ov > bv || (ov == bv && ol < bl);
          bv = t ? ov : bv; bl = t ? ol : bl;
        }
        if (lane == 0) g_neg[row * 32 + r] = bv;
        if (lane == bl) {
          #pragma unroll
          for (int s = 0; s < 31; ++s) ng[s] = ng[s + 1];
          ng[31] = -3.0e38f;
        }
      }
    }
  } else if (wid == 1) {
    // ---- rand: merge candidates -> 32 cols -> direct dots
    int cnt = g_rcnt[row];
    int stored = cnt < RCAP ? cnt : RCAP;
    int mycol = 0;
    unsigned kv[12]; int kj[12]; int nvalid = 0;
    #pragma unroll
    for (int q = 0; q < 12; ++q) {
      int ix = q * 64 + lane; bool ok = ix < stored;
      uint2 cd = ok ? g_cand[row * RCAP + ix] : make_uint2(0u, 0u);
      int m = ok ? (int)g_meta[cd.y] : 0;
      bool keep = ok && m != 0 && m != lab;
      kv[q] = keep ? cd.x : 0u;
      kj[q] = keep ? (int)cd.y : 0x7fffffff;
      nvalid += keep ? 1 : 0;
    }
    #pragma unroll
    for (int off = 32; off; off >>= 1) nvalid += __shfl_xor(nvalid, off);

    if (cnt <= RCAP && nvalid >= 32) {
      #pragma unroll 1
      for (int r = 0; r < 32; ++r) {
        unsigned bq = kv[0]; int bc = kj[0]; int bqi = 0;
        #pragma unroll
        for (int q = 1; q < 12; ++q) {
          bool t = kv[q] > bq || (kv[q] == bq && kj[q] < bc);
          bq = t ? kv[q] : bq; bc = t ? kj[q] : bc; bqi = t ? q : bqi;
        }
        int bl = lane;
        #pragma unroll
        for (int off = 32; off; off >>= 1) {
          unsigned oq = __shfl_xor(bq, off); int oc = __shfl_xor(bc, off); int ol = __shfl_xor(bl, off);
          bool t = oq > bq || (oq == bq && (oc < bc || (oc == bc && ol < bl)));
          bq = t ? oq : bq; bc = t ? oc : bc; bl = t ? ol : bl;
        }
        if (lane == bl) {
          #pragma unroll
          for (int q = 0; q < 12; ++q) { kv[q] = (q == bqi) ? 0u : kv[q]; kj[q] = (q == bqi) ? 0x7fffffff : kj[q]; }
        }
        if (lane == r) mycol = bc;
      }
    } else {
      // exact fallback: full re-hash (never taken on this data)
      const bool hif = row >= 512;
      const unsigned base = (unsigned)(hif ? row - 512 : row) << 16;
      unsigned rpv[32]; int rcc[32];
      #pragma unroll
      for (int s = 0; s < 32; ++s) { rpv[s] = 0u; rcc[s] = 0x7fffffff; }
      #pragma unroll 1
      for (int t = 0; t < 1024; ++t) {
        int j = t * 64 + lane;
        int m = g_meta[j];
        unsigned x0 = base + (unsigned)j;
        unsigned q = threefry_out(x0, x0 + 0x2000000u, hif) >> 9;
        if (m && m != lab && (q > rpv[31] || (q == rpv[31] && j < rcc[31]))) {
          #pragma unroll
          for (int s = 31; s >= 1; --s) {
            bool g1 = (q > rpv[s])   || (q == rpv[s]   && j < rcc[s]);
            bool g0 = (q > rpv[s-1]) || (q == rpv[s-1] && j < rcc[s-1]);
            unsigned np2 = g1 ? (g0 ? rpv[s-1] : q) : rpv[s];
            int      nc2 = g1 ? (g0 ? rcc[s-1] : j) : rcc[s];
            rpv[s] = np2; rcc[s] = nc2;
          }
          if (q > rpv[0] || (q == rpv[0] && j < rcc[0])) { rpv[0] = q; rcc[0] = j; }
        }
      }
      #pragma unroll 1
      for (int r = 0; r < 32; ++r) {
        unsigned bq = rpv[0]; int bc = rcc[0]; int bl = lane;
        #pragma unroll
        for (int off = 32; off; off >>= 1) {
          unsigned oq = __shfl_xor(bq, off); int oc = __shfl_xor(bc, off); int ol = __shfl_xor(bl, off);
          bool t = oq > bq || (oq == bq && (oc < bc || (oc == bc && ol < bl)));
          bq = t ? oq : bq; bc = t ? oc : bc; bl = t ? ol : bl;
        }
        if (lane == bl) {
          #pragma unroll
          for (int s = 0; s < 31; ++s) { rpv[s] = rpv[s + 1]; rcc[s] = rcc[s + 1]; }
          rpv[31] = 0u; rcc[31] = 0x7fffffff;
        }
        if (lane == r) mycol = bc;
      }
    }
    // direct dots for the 32 columns
    uint2 fw = *(const uint2*)(g_fnb + (size_t)row * DOUT + lane * 4);
    float fr0 = bflo(fw.x), fr1 = bfhi(fw.x), fr2 = bflo(fw.y), fr3 = bfhi(fw.y);
    float myrnd = 0.f;
    #pragma unroll 4
    for (int c = 0; c < 32; ++c) {
      int col = __shfl(mycol, c);
      col = ((unsigned)col < MEMN) ? col : 0;
      uint2 bw = *(const uint2*)(g_bank2b + (size_t)col * DOUT + lane * 4);
      float p = fr0 * bflo(bw.x) + fr1 * bfhi(bw.x) + fr2 * bflo(bw.y) + fr3 * bfhi(bw.y);
      #pragma unroll
      for (int off = 32; off; off >>= 1) p += __shfl_xor(p, off);
      if (lane == c) myrnd = p;
    }
    if (lane < 32) g_rnd[row * 32 + lane] = myrnd;
  } else {
    // ---- 8 smallest positives
    int pcq = g_pcnt[row];
    if (pcq <= 1024) {
      float vals[16];
      #pragma unroll
      for (int q = 0; q < 16; ++q) { int ix = q * 64 + lane; vals[q] = ix < pcq ? g_posv[row * 1024 + ix] : 3.0e38f; }
      #pragma unroll 1
      for (int r = 0; r < 8; ++r) {
        float bv = vals[0]; int bq = 0;
        #pragma unroll
        for (int q = 1; q < 16; ++q) { bool t = vals[q] < bv; bv = t ? vals[q] : bv; bq = t ? q : bq; }
        int bl = lane;
        #pragma unroll
        for (int off = 32; off; off >>= 1) {
          float ov = __shfl_xor(bv, off); int ol = __shfl_xor(bl, off);
          bool t = ov < bv || (ov == bv && ol < bl);
          bv = t ? ov : bv; bl = t ? ol : bl;
        }
        if (lane == bl) {
          #pragma unroll
          for (int q = 0; q < 16; ++q) vals[q] = (q == bq) ? 3.0e38f : vals[q];
        }
        if (lane == 0) g_pos[row * 8 + r] = bv;
      }
    } else {
      // exact fallback: recompute positive dots (never taken on this data)
      float pv[8];
      #pragma unroll
      for (int s = 0; s < 8; ++s) pv[s] = 3.0e38f;
      #pragma unroll 1
      for (int c0 = 0; c0 < 1024; ++c0) {
        int col = c0 * 64 + lane;
        if ((int)g_meta[col] != lab) continue;
        const uint2* br = (const uint2*)(g_bank2b + (size_t)col * DOUT);
        float d = 0.f;
        #pragma unroll 8
        for (int k = 0; k < 64; ++k) {
          uint2 wv = br[k];
          d += s_fnf[k*4+0] * bflo(wv.x) + s_fnf[k*4+1] * bfhi(wv.x)
             + s_fnf[k*4+2] * bflo(wv.y) + s_fnf[k*4+3] * bfhi(wv.y);
        }
        if (d < pv[7]) {
          #pragma unroll
          for (int s = 7; s >= 1; --s) pv[s] = (d < pv[s]) ? ((d < pv[s-1]) ? pv[s-1] : d) : pv[s];
          pv[0] = (d < pv[0]) ? d : pv[0];
        }
      }
      #pragma unroll 1
      for (int r = 0; r < 8; ++r) {
        float bv = pv[0]; int bl = lane;
        #pragma unroll
        for (int off = 32; off; off >>= 1) {
          float ov = __shfl_xor(bv, off); int ol = __shfl_xor(bl, off);
          bool t = ov < bv || (ov == bv && ol < bl);
          bv = t ? ov : bv; bl = t ? ol : bl;
        }
        if (lane == 0) g_pos[row * 8 + r] = bv;
        if (lane == bl) {
          #pragma unroll
          for (int s = 0; s < 7; ++s) pv[s] = pv[s + 1];
          pv[7] = 3.0e38f;
        }
      }
    }
  }
}

// ---------------- fused per-row loss + final reduction (1 block) ------------
__global__ __launch_bounds__(1024) void k_loss_final(const int* label, float* out) {
  __shared__ float sl[1024];
  __shared__ int sc[1024];
  const int i = threadIdx.x;            // one row per thread
  float psum = g_clssum[label[i]];
  float nsum = g_clssum[155] - psum;
  int valid = (psum >= 8.0f) && (nsum >= 32.0f);
  float loss = 0.0f;
  if (valid) {
    const float invT = 1.25f;
    float nh[32], nr[32];
    float m1 = -3.0e38f, m2 = -3.0e38f;
    #pragma unroll
    for (int k = 0; k < 32; ++k) {
      nh[k] = g_neg[i * 32 + k] * invT; m1 = fmaxf(m1, nh[k]);
      nr[k] = g_rnd[i * 32 + k] * invT; m2 = fmaxf(m2, nr[k]);
    }
    float s1 = 0.0f, s2 = 0.0f;
    #pragma unroll
    for (int k = 0; k < 32; ++k) { s1 += expf(nh[k] - m1); s2 += expf(nr[k] - m2); }
    #pragma unroll
    for (int p = 0; p < 8; ++p) {
      float a = g_pos[i * 8 + p] * invT;
      { float m = fmaxf(a, m1); loss += m + logf(expf(a - m) + s1 * expf(m1 - m)) - a; }
      { float m = fmaxf(a, m2); loss += m + logf(expf(a - m) + s2 * expf(m2 - m)) - a; }
    }
  }
  sl[i] = loss; sc[i] = valid;
  __syncthreads();
  for (int s = 512; s > 0; s >>= 1) {
    if (i < s) { sl[i] += sl[i + s]; sc[i] += sc[i + s]; }
    __syncthreads();
  }
  if (i == 0) out[0] = (sc[0] > 0) ? sl[0] / ((float)sc[0] * 16.0f) : 0.0f;
}

// ---------------- launch ----------------------------------------------------
extern "C" void kernel_launch(void* const* d_in, const int* in_sizes, int n_in,
                              void* d_out, int out_size, void* d_ws, size_t ws_size,
                              hipStream_t stream) {
  const float* f          = (const float*)d_in[0];
  const float* W          = (const float*)d_in[1];
  const float* b          = (const float*)d_in[2];
  const float* Bank       = (const float*)d_in[3];
  const float* bank_flag  = (const float*)d_in[4];
  const int*   label      = (const int*)d_in[5];
  const long long* in_idx = (const long long*)d_in[6];
  const int*   label_all  = (const int*)d_in[7];
  float* out = (float*)d_out;

  hipLaunchKernelGGL(k_owner_init,    dim3(MEMN / 256), dim3(256), 0, stream);
  hipLaunchKernelGGL(k_owner_scatter, dim3(NROW / 256), dim3(256), 0, stream, in_idx);
  hipLaunchKernelGGL(k_meta,          dim3(MEMN / 256), dim3(256), 0, stream, bank_flag, label_all);
  hipLaunchKernelGGL(k_fn,            dim3(NROW),       dim3(256), 0, stream, f, W, b);
  hipLaunchKernelGGL(k_bank2,         dim3(MEMN / 4),   dim3(256), 0, stream, Bank);
  hipLaunchKernelGGL(k_gemm_rand,     dim3(4096),       dim3(256), 0, stream);
  hipLaunchKernelGGL(k_scan,          dim3(NROW * 8),   dim3(256), 0, stream, label);
  hipLaunchKernelGGL(k_select,        dim3(NROW),       dim3(192), 0, stream, label);
  hipLaunchKernelGGL(k_loss_final,    dim3(1),          dim3(1024), 0, stream, label, out);
}

// Round 16
// 267.328 us; speedup vs baseline: 1.0276x; 1.0276x over previous
//
#include <hip/hip_runtime.h>
#include <math.h>

#define NROW 1024
#define DIN  128
#define DOUT 256
#define MEMN 65536
#define QTHB  4286377472u   // full-bits threshold (== (bits>>9) >= 8371831)
#define RCAP  768

typedef __attribute__((ext_vector_type(8))) short bf16x8;
typedef __attribute__((ext_vector_type(4))) float f32x4;
typedef __attribute__((ext_vector_type(8))) unsigned short u16x8;

// ---------------- static device scratch ------------------------------------
__device__ unsigned short g_fnb[NROW * DOUT];
__device__ unsigned short g_bank2b[(size_t)MEMN * DOUT];
__device__ unsigned short g_pairsb[(size_t)NROW * MEMN];     // 128 MB bf16
__device__ int            g_owner[MEMN];
__device__ unsigned short g_meta[MEMN];                      // label+1 if flag2>0 else 0
__device__ float          g_clssum[156];
__device__ float          g_posv[NROW * 1024];               // per-row positive values (f32)
__device__ int            g_pcnt[NROW];
__device__ float          g_negv[NROW * 512];                // per-row neg values >= floor
__device__ int            g_ncnt[NROW];
__device__ uint2          g_cand[NROW * RCAP];               // rand candidates (q, col)
__device__ int            g_rcnt[NROW];
__device__ float          g_pos[NROW * 8];
__device__ float          g_neg[NROW * 32];
__device__ float          g_rnd[NROW * 32];
__device__ float          g_rowloss[NROW];
__device__ int            g_rowvalid[NROW];

__device__ __forceinline__ unsigned short f2bf(float x) {
  union { float f; unsigned u; } c; c.f = x;
  unsigned r = c.u + 0x7fffu + ((c.u >> 16) & 1u);
  return (unsigned short)(r >> 16);
}
__device__ __forceinline__ float bf2f(unsigned short b) {
  return __uint_as_float((unsigned)b << 16);
}
__device__ __forceinline__ float bflo(unsigned u) { return __uint_as_float(u << 16); }
__device__ __forceinline__ float bfhi(unsigned u) { return __uint_as_float(u & 0xffff0000u); }

// ---------------- threefry2x32 key=(0,1) -----------------------------------
#define ROTL(x, r) (((x) << (r)) | ((x) >> (32 - (r))))
#define TF_R2(r) { a0 += a1; a1 = ROTL(a1, r); a1 ^= a0; \
                   b0 += b1; b1 = ROTL(b1, r); b1 ^= b0; }
__device__ __forceinline__ void tf2(unsigned &a0, unsigned &a1, unsigned &b0, unsigned &b1) {
  const unsigned ks1 = 1u, ks2 = 0x1BD11BDBu;
  a1 += ks1; b1 += ks1;
  TF_R2(13) TF_R2(15) TF_R2(26) TF_R2(6)
  a0 += ks1; a1 += ks2 + 1u; b0 += ks1; b1 += ks2 + 1u;
  TF_R2(17) TF_R2(29) TF_R2(16) TF_R2(24)
  a0 += ks2; a1 += 2u;       b0 += ks2; b1 += 2u;
  TF_R2(13) TF_R2(15) TF_R2(26) TF_R2(6)
  a1 += ks1 + 3u;            b1 += ks1 + 3u;
  TF_R2(17) TF_R2(29) TF_R2(16) TF_R2(24)
  a0 += ks1; a1 += ks2 + 4u; b0 += ks1; b1 += ks2 + 4u;
  TF_R2(13) TF_R2(15) TF_R2(26) TF_R2(6)
  a0 += ks2; a1 += 5u;       b0 += ks2; b1 += 5u;
}
__device__ __forceinline__ void tfround(unsigned &x0, unsigned &x1, int r) {
  x0 += x1; x1 = ROTL(x1, r); x1 ^= x0;
}
__device__ __forceinline__ unsigned threefry_out(unsigned x0, unsigned x1, bool hi) {
  const unsigned ks1 = 1u, ks2 = 0x1BD11BDBu;
  x1 += ks1;
  tfround(x0,x1,13); tfround(x0,x1,15); tfround(x0,x1,26); tfround(x0,x1,6);
  x0 += ks1; x1 += ks2 + 1u;
  tfround(x0,x1,17); tfround(x0,x1,29); tfround(x0,x1,16); tfround(x0,x1,24);
  x0 += ks2; x1 += 2u;
  tfround(x0,x1,13); tfround(x0,x1,15); tfround(x0,x1,26); tfround(x0,x1,6);
  x1 += ks1 + 3u;
  tfround(x0,x1,17); tfround(x0,x1,29); tfround(x0,x1,16); tfround(x0,x1,24);
  x0 += ks1; x1 += ks2 + 4u;
  tfround(x0,x1,13); tfround(x0,x1,15); tfround(x0,x1,26); tfround(x0,x1,6);
  x0 += ks2; x1 += 5u;
  return hi ? x1 : x0;
}

// ---------------- prep kernels ----------------------------------------------
__global__ void k_owner_init() {
  int j = blockIdx.x * 256 + threadIdx.x;
  g_owner[j] = -1;
  if (j < 156) g_clssum[j] = 0.0f;
  if (j < NROW) { g_rcnt[j] = 0; g_pcnt[j] = 0; g_ncnt[j] = 0; }
}
__global__ void k_owner_scatter(const long long* idx) {
  int i = blockIdx.x * 256 + threadIdx.x;
  if (i < NROW) atomicMax(&g_owner[(int)idx[i]], i);
}
__global__ void k_meta(const float* bank_flag, const int* label_all) {
  __shared__ float s_cls[156];
  int t = threadIdx.x;
  int j = blockIdx.x * 256 + t;
  if (t < 156) s_cls[t] = 0.0f;
  __syncthreads();
  float fl = (g_owner[j] >= 0) ? 1.0f : bank_flag[j];
  int la = label_all[j];
  unsigned short m = (fl > 0.0f) ? (unsigned short)(la + 1) : (unsigned short)0;
  g_meta[j] = m;
  if (m) { atomicAdd(&s_cls[la], fl); atomicAdd(&s_cls[155], fl); }
  __syncthreads();
  if (t < 156 && s_cls[t] != 0.0f) atomicAdd(&g_clssum[t], s_cls[t]);
}

__global__ __launch_bounds__(256) void k_fn(const float* f, const float* W, const float* b) {
  int i = blockIdx.x, t = threadIdx.x;
  __shared__ __align__(16) float sf[DIN];
  __shared__ float sred[256];
  if (t < DIN / 4) ((float4*)sf)[t] = ((const float4*)(f + (size_t)i * DIN))[t];
  __syncthreads();
  const float4* wrow = (const float4*)(W + (size_t)t * DIN);
  float acc = 0.0f;
  #pragma unroll
  for (int k = 0; k < DIN / 4; ++k) {
    float4 wv = wrow[k]; float4 fv = ((float4*)sf)[k];
    acc = fmaf(wv.x, fv.x, acc); acc = fmaf(wv.y, fv.y, acc);
    acc = fmaf(wv.z, fv.z, acc); acc = fmaf(wv.w, fv.w, acc);
  }
  acc += b[t];
  sred[t] = acc * acc;
  __syncthreads();
  for (int s = 128; s > 0; s >>= 1) { if (t < s) sred[t] += sred[t + s]; __syncthreads(); }
  g_fnb[(size_t)i * DOUT + t] = f2bf(acc * (1.0f / sqrtf(sred[0])));
}

__global__ __launch_bounds__(256) void k_bank2(const float* Bank) {
  int j = blockIdx.x * 4 + (threadIdx.x >> 6);
  int t = threadIdx.x & 63;
  int own = g_owner[j];
  uint2 o;
  if (own >= 0) {
    o = ((const uint2*)(g_fnb + (size_t)own * DOUT))[t];
  } else {
    float4 v = ((const float4*)(Bank + (size_t)j * DOUT))[t];
    o.x = (unsigned)f2bf(v.x) | ((unsigned)f2bf(v.y) << 16);
    o.y = (unsigned)f2bf(v.z) | ((unsigned)f2bf(v.w) << 16);
  }
  ((uint2*)(g_bank2b + (size_t)j * DOUT))[t] = o;
}

// ---------------- fused: GEMM tile + post-epilogue rand slice ---------------
#define GBK 32
__device__ __forceinline__ void gload16(const void* g, void* l) {
  __builtin_amdgcn_global_load_lds((const __attribute__((address_space(1))) void*)g,
                                   (__attribute__((address_space(3))) void*)l, 16, 0, 0);
}

__global__ __launch_bounds__(256) void k_gemm_rand() {
  __shared__ __align__(16) unsigned short lds[2][2][128 * GBK];
  const int tid = threadIdx.x, lane = tid & 63, w = tid >> 6;
  int bid = blockIdx.x;
  int swz = (bid & 7) * 512 + (bid >> 3);
  const int row0 = (swz & 7) * 128, col0 = (swz >> 3) * 128;
  const int wm = w >> 1, wn = w & 1;

  f32x4 acc[4][4];
  #pragma unroll
  for (int i = 0; i < 4; ++i)
    #pragma unroll
    for (int j = 0; j < 4; ++j) acc[i][j] = (f32x4){0.f, 0.f, 0.f, 0.f};

  int aoff[4], boff[4];
  #pragma unroll
  for (int mf = 0; mf < 4; ++mf) {
    int ra = wm * 64 + mf * 16 + (lane & 15);
    int ca = (lane >> 4) ^ ((ra >> 1) & 3);
    aoff[mf] = ra * GBK + ca * 8;
    int rb = wn * 64 + mf * 16 + (lane & 15);
    int cb2 = (lane >> 4) ^ ((rb >> 1) & 3);
    boff[mf] = rb * GBK + cb2 * 8;
  }

  auto stage = [&](int buf, int kt) {
    #pragma unroll
    for (int q = 0; q < 2; ++q) {
      int g  = w * 2 + q;
      int ci = g * 64 + lane;
      int r  = ci >> 2, c = ci & 3;
      int cs = c ^ ((r >> 1) & 3);
      gload16(g_fnb    + (size_t)(row0 + r) * DOUT + kt + cs * 8, &lds[buf][0][g * 512]);
      gload16(g_bank2b + (size_t)(col0 + r) * DOUT + kt + cs * 8, &lds[buf][1][g * 512]);
    }
  };

  stage(0, 0);
  __syncthreads();
  int cur = 0;
  for (int kt = 0; kt < DOUT; kt += GBK) {
    if (kt + GBK < DOUT) stage(cur ^ 1, kt + GBK);
    bf16x8 af[4], bf_[4];
    #pragma unroll
    for (int mf = 0; mf < 4; ++mf) af[mf]  = *(const bf16x8*)&lds[cur][0][aoff[mf]];
    #pragma unroll
    for (int nf = 0; nf < 4; ++nf) bf_[nf] = *(const bf16x8*)&lds[cur][1][boff[nf]];
    #pragma unroll
    for (int mf = 0; mf < 4; ++mf)
      #pragma unroll
      for (int nf = 0; nf < 4; ++nf)
        acc[mf][nf] = __builtin_amdgcn_mfma_f32_16x16x32_bf16(bf_[nf], af[mf], acc[mf][nf], 0, 0, 0);
    __syncthreads();
    cur ^= 1;
  }

  #pragma unroll
  for (int mf = 0; mf < 4; ++mf) {
    int rg = row0 + wm * 64 + mf * 16 + (lane & 15);
    #pragma unroll
    for (int nf = 0; nf < 4; ++nf) {
      int cg = col0 + wn * 64 + nf * 16 + ((lane >> 4) << 2);
      uint2 o;
      o.x = (unsigned)f2bf(acc[mf][nf][0]) | ((unsigned)f2bf(acc[mf][nf][1]) << 16);
      o.y = (unsigned)f2bf(acc[mf][nf][2]) | ((unsigned)f2bf(acc[mf][nf][3]) << 16);
      *(uint2*)(g_pairsb + (size_t)rg * MEMN + cg) = o;
    }
  }

  // ---- rand phase: slice (rp = bid>>3, sub = bid&7), 8192 j per block -----
  int* s_cnt = (int*)&lds[0][0][0];           // 2 counters
  uint2* s_rbuf = (uint2*)(s_cnt + 4);        // [2][64] candidates
  __syncthreads();                            // staging LDS now dead
  if (tid < 2) s_cnt[tid] = 0;
  __syncthreads();
  const int rp = bid >> 3, sub = bid & 7;
  const unsigned rbase = (unsigned)rp << 16;
  const int j0 = sub * 8192 + tid;
  #pragma unroll 2
  for (int it = 0; it < 16; ++it) {
    const int jA = j0 + it * 256;
    const int jB = jA + 4096;
    unsigned a0 = rbase + (unsigned)jA, a1 = a0 + 0x2000000u;
    unsigned b0 = rbase + (unsigned)jB, b1 = b0 + 0x2000000u;
    tf2(a0, a1, b0, b1);
    if (a0 >= QTHB || a1 >= QTHB || b0 >= QTHB || b1 >= QTHB) {
      if (a0 >= QTHB) { int p = atomicAdd(&s_cnt[0], 1); if (p < 64) s_rbuf[p]      = make_uint2(a0 >> 9, (unsigned)jA); }
      if (a1 >= QTHB) { int p = atomicAdd(&s_cnt[1], 1); if (p < 64) s_rbuf[64 + p] = make_uint2(a1 >> 9, (unsigned)jA); }
      if (b0 >= QTHB) { int p = atomicAdd(&s_cnt[0], 1); if (p < 64) s_rbuf[p]      = make_uint2(b0 >> 9, (unsigned)jB); }
      if (b1 >= QTHB) { int p = atomicAdd(&s_cnt[1], 1); if (p < 64) s_rbuf[64 + p] = make_uint2(b1 >> 9, (unsigned)jB); }
    }
  }
  __syncthreads();
  if (w < 2) {
    int cl = s_cnt[w];
    int row = rp + w * 512;
    int adv = (cl <= 64) ? cl : (RCAP + 1024);    // overflow -> force fallback
    int base_ = 0;
    if (lane == 0) base_ = atomicAdd(&g_rcnt[row], adv);
    base_ = __shfl(base_, 0);
    int n = cl < 64 ? cl : 64;
    if (lane < n) {
      int dst = base_ + lane;
      if (dst < RCAP) g_cand[row * RCAP + dst] = s_rbuf[w * 64 + lane];
    }
  }
}

// ---------------- scan pairs -> per-row pos/neg lists (8 blocks/row) --------
#define SPCAP 160
#define SNCAP 96
__global__ __launch_bounds__(256) void k_scan(const int* label) {
  const int row = blockIdx.x >> 3, s = blockIdx.x & 7;
  const int tid = threadIdx.x;
  __shared__ float s_pb[SPCAP];
  __shared__ float s_nb[SNCAP];
  __shared__ int s_pc, s_nc, s_pbase, s_nbase;
  if (tid == 0) { s_pc = 0; s_nc = 0; }
  __syncthreads();
  const int lab = label[row] + 1;
  const unsigned short* prow = g_pairsb + (size_t)row * MEMN + s * 8192;
  const unsigned short* mrow = g_meta + s * 8192;

  #pragma unroll
  for (int it = 0; it < 4; ++it) {
    int p8 = it * 256 + tid;                       // 0..1023
    u16x8 pb = *(const u16x8*)(prow + p8 * 8);
    u16x8 mb = *(const u16x8*)(mrow + p8 * 8);
    unsigned pm = 0, nm = 0;
    #pragma unroll
    for (int q = 0; q < 8; ++q) {
      int m = mb[q];
      unsigned isp = (unsigned)(m == lab);
      unsigned isn = (unsigned)((m != 0) & (m != lab) & ((short)pb[q] >= (short)0x3E40));
      pm |= isp << q;
      nm |= isn << q;
    }
    while (pm) { int q = __builtin_ctz(pm); pm &= pm - 1; int ix = atomicAdd(&s_pc, 1); if (ix < SPCAP) s_pb[ix] = bf2f(pb[q]); }
    while (nm) { int q = __builtin_ctz(nm); nm &= nm - 1; int ix = atomicAdd(&s_nc, 1); if (ix < SNCAP) s_nb[ix] = bf2f(pb[q]); }
  }
  __syncthreads();
  if (tid == 0) {
    int c = s_pc;
    s_pbase = atomicAdd(&g_pcnt[row], (c <= SPCAP) ? c : 100000);
  } else if (tid == 64) {
    int c = s_nc;
    s_nbase = atomicAdd(&g_ncnt[row], (c <= SNCAP) ? c : 100000);
  }
  __syncthreads();
  int pc = s_pc < SPCAP ? s_pc : SPCAP;
  int nc = s_nc < SNCAP ? s_nc : SNCAP;
  for (int ix = tid; ix < pc; ix += 256) { int d = s_pbase + ix; if (d < 1024) g_posv[row * 1024 + d] = s_pb[ix]; }
  for (int ix = tid; ix < nc; ix += 256) { int d = s_nbase + ix; if (d < 512)  g_negv[row * 512 + d]  = s_nb[ix]; }
}

// ---------------- per-row selection from lists -------------------------------
__global__ __launch_bounds__(192) void k_select(const int* label) {
  const int row = blockIdx.x, tid = threadIdx.x, lane = tid & 63, wid = tid >> 6;
  __shared__ float s_fnf[256];
  for (int i = tid; i < 256; i += 192) s_fnf[i] = bf2f(g_fnb[(size_t)row * DOUT + i]);
  __syncthreads();
  const int lab = label[row] + 1;

  if (wid == 0) {
    // ---- top-32 negatives
    int ncq = g_ncnt[row];
    if (ncq >= 32 && ncq <= 512) {
      float vals[8];
      #pragma unroll
      for (int q = 0; q < 8; ++q) { int ix = q * 64 + lane; vals[q] = ix < ncq ? g_negv[row * 512 + ix] : -3.0e38f; }
      #pragma unroll 1
      for (int r = 0; r < 32; ++r) {
        float bv = vals[0]; int bq = 0;
        #pragma unroll
        for (int q = 1; q < 8; ++q) { bool t = vals[q] > bv; bv = t ? vals[q] : bv; bq = t ? q : bq; }
        int bl = lane;
        #pragma unroll
        for (int off = 32; off; off >>= 1) {
          float ov = __shfl_xor(bv, off); int ol = __shfl_xor(bl, off);
          bool t = ov > bv || (ov == bv && ol < bl);
          bv = t ? ov : bv; bl = t ? ol : bl;
        }
        if (lane == bl) {
          #pragma unroll
          for (int q = 0; q < 8; ++q) vals[q] = (q == bq) ? -3.0e38f : vals[q];
        }
        if (lane == 0) g_neg[row * 32 + r] = bv;
      }
    } else {
      // exact fallback: recompute all dots (never taken on this data)
      float ng[32];
      #pragma unroll
      for (int s = 0; s < 32; ++s) ng[s] = -3.0e38f;
      #pragma unroll 1
      for (int c0 = 0; c0 < 1024; ++c0) {
        int col = c0 * 64 + lane;
        int m = g_meta[col];
        if (m == 0 || m == lab) continue;
        const uint2* br = (const uint2*)(g_bank2b + (size_t)col * DOUT);
        float d = 0.f;
        #pragma unroll 8
        for (int k = 0; k < 64; ++k) {
          uint2 wv = br[k];
          d += s_fnf[k*4+0] * bflo(wv.x) + s_fnf[k*4+1] * bfhi(wv.x)
             + s_fnf[k*4+2] * bflo(wv.y) + s_fnf[k*4+3] * bfhi(wv.y);
        }
        if (d > ng[31]) {
          #pragma unroll
          for (int s = 31; s >= 1; --s) ng[s] = (d > ng[s]) ? ((d > ng[s-1]) ? ng[s-1] : d) : ng[s];
          ng[0] = (d > ng[0]) ? d : ng[0];
        }
      }
      #pragma unroll 1
      for (int r = 0; r < 32; ++r) {
        float bv = ng[0]; int bl = lane;
        #pragma unroll
        for (int off = 32; off; off >>= 1) {
          float ov = __shfl_xor(bv, off); int ol = __shfl_xor(bl, off);
          bool t = ov > bv || (ov == bv && ol < bl);
          bv = t ? ov : bv; bl = t ? ol : bl;
        }
        if (lane == 0) g_neg[row * 32 + r] = bv;
        if (lane == bl) {
          #pragma unroll
          for (int s = 0; s < 31; ++s) ng[s] = ng[s + 1];
          ng[31] = -3.0e38f;
        }
      }
    }
  } else if (wid == 1) {
    // ---- rand: merge candidates -> 32 cols -> direct dots
    int cnt = g_rcnt[row];
    int stored = cnt < RCAP ? cnt : RCAP;
    int mycol = 0;
    unsigned kv[12]; int kj[12]; int nvalid = 0;
    #pragma unroll
    for (int q = 0; q < 12; ++q) {
      int ix = q * 64 + lane; bool ok = ix < stored;
      uint2 cd = ok ? g_cand[row * RCAP + ix] : make_uint2(0u, 0u);
      int m = ok ? (int)g_meta[cd.y] : 0;
      bool keep = ok && m != 0 && m != lab;
      kv[q] = keep ? cd.x : 0u;
      kj[q] = keep ? (int)cd.y : 0x7fffffff;
      nvalid += keep ? 1 : 0;
    }
    #pragma unroll
    for (int off = 32; off; off >>= 1) nvalid += __shfl_xor(nvalid, off);

    if (cnt <= RCAP && nvalid >= 32) {
      #pragma unroll 1
      for (int r = 0; r < 32; ++r) {
        unsigned bq = kv[0]; int bc = kj[0]; int bqi = 0;
        #pragma unroll
        for (int q = 1; q < 12; ++q) {
          bool t = kv[q] > bq || (kv[q] == bq && kj[q] < bc);
          bq = t ? kv[q] : bq; bc = t ? kj[q] : bc; bqi = t ? q : bqi;
        }
        int bl = lane;
        #pragma unroll
        for (int off = 32; off; off >>= 1) {
          unsigned oq = __shfl_xor(bq, off); int oc = __shfl_xor(bc, off); int ol = __shfl_xor(bl, off);
          bool t = oq > bq || (oq == bq && (oc < bc || (oc == bc && ol < bl)));
          bq = t ? oq : bq; bc = t ? oc : bc; bl = t ? ol : bl;
        }
        if (lane == bl) {
          #pragma unroll
          for (int q = 0; q < 12; ++q) { kv[q] = (q == bqi) ? 0u : kv[q]; kj[q] = (q == bqi) ? 0x7fffffff : kj[q]; }
        }
        if (lane == r) mycol = bc;
      }
    } else {
      // exact fallback: full re-hash (never taken on this data)
      const bool hif = row >= 512;
      const unsigned base = (unsigned)(hif ? row - 512 : row) << 16;
      unsigned rpv[32]; int rcc[32];
      #pragma unroll
      for (int s = 0; s < 32; ++s) { rpv[s] = 0u; rcc[s] = 0x7fffffff; }
      #pragma unroll 1
      for (int t = 0; t < 1024; ++t) {
        int j = t * 64 + lane;
        int m = g_meta[j];
        unsigned x0 = base + (unsigned)j;
        unsigned q = threefry_out(x0, x0 + 0x2000000u, hif) >> 9;
        if (m && m != lab && (q > rpv[31] || (q == rpv[31] && j < rcc[31]))) {
          #pragma unroll
          for (int s = 31; s >= 1; --s) {
            bool g1 = (q > rpv[s])   || (q == rpv[s]   && j < rcc[s]);
            bool g0 = (q > rpv[s-1]) || (q == rpv[s-1] && j < rcc[s-1]);
            unsigned np2 = g1 ? (g0 ? rpv[s-1] : q) : rpv[s];
            int      nc2 = g1 ? (g0 ? rcc[s-1] : j) : rcc[s];
            rpv[s] = np2; rcc[s] = nc2;
          }
          if (q > rpv[0] || (q == rpv[0] && j < rcc[0])) { rpv[0] = q; rcc[0] = j; }
        }
      }
      #pragma unroll 1
      for (int r = 0; r < 32; ++r) {
        unsigned bq = rpv[0]; int bc = rcc[0]; int bl = lane;
        #pragma unroll
        for (int off = 32; off; off >>= 1) {
          unsigned oq = __shfl_xor(bq, off); int oc = __shfl_xor(bc, off); int ol = __shfl_xor(bl, off);
          bool t = oq > bq || (oq == bq && (oc < bc || (oc == bc && ol < bl)));
          bq = t ? oq : bq; bc = t ? oc : bc; bl = t ? ol : bl;
        }
        if (lane == bl) {
          #pragma unroll
          for (int s = 0; s < 31; ++s) { rpv[s] = rpv[s + 1]; rcc[s] = rcc[s + 1]; }
          rpv[31] = 0u; rcc[31] = 0x7fffffff;
        }
        if (lane == r) mycol = bc;
      }
    }
    // direct dots for the 32 columns
    uint2 fw = *(const uint2*)(g_fnb + (size_t)row * DOUT + lane * 4);
    float fr0 = bflo(fw.x), fr1 = bfhi(fw.x), fr2 = bflo(fw.y), fr3 = bfhi(fw.y);
    float myrnd = 0.f;
    #pragma unroll 4
    for (int c = 0; c < 32; ++c) {
      int col = __shfl(mycol, c);
      col = ((unsigned)col < MEMN) ? col : 0;
      uint2 bw = *(const uint2*)(g_bank2b + (size_t)col * DOUT + lane * 4);
      float p = fr0 * bflo(bw.x) + fr1 * bfhi(bw.x) + fr2 * bflo(bw.y) + fr3 * bfhi(bw.y);
      #pragma unroll
      for (int off = 32; off; off >>= 1) p += __shfl_xor(p, off);
      if (lane == c) myrnd = p;
    }
    if (lane < 32) g_rnd[row * 32 + lane] = myrnd;
  } else {
    // ---- 8 smallest positives
    int pcq = g_pcnt[row];
    if (pcq <= 1024) {
      float vals[16];
      #pragma unroll
      for (int q = 0; q < 16; ++q) { int ix = q * 64 + lane; vals[q] = ix < pcq ? g_posv[row * 1024 + ix] : 3.0e38f; }
      #pragma unroll 1
      for (int r = 0; r < 8; ++r) {
        float bv = vals[0]; int bq = 0;
        #pragma unroll
        for (int q = 1; q < 16; ++q) { bool t = vals[q] < bv; bv = t ? vals[q] : bv; bq = t ? q : bq; }
        int bl = lane;
        #pragma unroll
        for (int off = 32; off; off >>= 1) {
          float ov = __shfl_xor(bv, off); int ol = __shfl_xor(bl, off);
          bool t = ov < bv || (ov == bv && ol < bl);
          bv = t ? ov : bv; bl = t ? ol : bl;
        }
        if (lane == bl) {
          #pragma unroll
          for (int q = 0; q < 16; ++q) vals[q] = (q == bq) ? 3.0e38f : vals[q];
        }
        if (lane == 0) g_pos[row * 8 + r] = bv;
      }
    } else {
      // exact fallback: recompute positive dots (never taken on this data)
      float pv[8];
      #pragma unroll
      for (int s = 0; s < 8; ++s) pv[s] = 3.0e38f;
      #pragma unroll 1
      for (int c0 = 0; c0 < 1024; ++c0) {
        int col = c0 * 64 + lane;
        if ((int)g_meta[col] != lab) continue;
        const uint2* br = (const uint2*)(g_bank2b + (size_t)col * DOUT);
        float d = 0.f;
        #pragma unroll 8
        for (int k = 0; k < 64; ++k) {
          uint2 wv = br[k];
          d += s_fnf[k*4+0] * bflo(wv.x) + s_fnf[k*4+1] * bfhi(wv.x)
             + s_fnf[k*4+2] * bflo(wv.y) + s_fnf[k*4+3] * bfhi(wv.y);
        }
        if (d < pv[7]) {
          #pragma unroll
          for (int s = 7; s >= 1; --s) pv[s] = (d < pv[s]) ? ((d < pv[s-1]) ? pv[s-1] : d) : pv[s];
          pv[0] = (d < pv[0]) ? d : pv[0];
        }
      }
      #pragma unroll 1
      for (int r = 0; r < 8; ++r) {
        float bv = pv[0]; int bl = lane;
        #pragma unroll
        for (int off = 32; off; off >>= 1) {
          float ov = __shfl_xor(bv, off); int ol = __shfl_xor(bl, off);
          bool t = ov < bv || (ov == bv && ol < bl);
          bv = t ? ov : bv; bl = t ? ol : bl;
        }
        if (lane == 0) g_pos[row * 8 + r] = bv;
        if (lane == bl) {
          #pragma unroll
          for (int s = 0; s < 7; ++s) pv[s] = pv[s + 1];
          pv[7] = 3.0e38f;
        }
      }
    }
  }
}

// ---------------- per-row loss ----------------------------------------------
__global__ __launch_bounds__(256) void k_loss(const int* label) {
  int i = blockIdx.x * 256 + threadIdx.x;
  if (i >= NROW) return;
  float psum = g_clssum[label[i]];
  float nsum = g_clssum[155] - psum;
  int valid = (psum >= 8.0f) && (nsum >= 32.0f);
  float loss = 0.0f;
  if (valid) {
    const float invT = 1.25f;
    float nh[32], nr[32];
    float m1 = -3.0e38f, m2 = -3.0e38f;
    #pragma unroll
    for (int k = 0; k < 32; ++k) {
      nh[k] = g_neg[i * 32 + k] * invT; m1 = fmaxf(m1, nh[k]);
      nr[k] = g_rnd[i * 32 + k] * invT; m2 = fmaxf(m2, nr[k]);
    }
    float s1 = 0.0f, s2 = 0.0f;
    #pragma unroll
    for (int k = 0; k < 32; ++k) { s1 += expf(nh[k] - m1); s2 += expf(nr[k] - m2); }
    #pragma unroll
    for (int p = 0; p < 8; ++p) {
      float a = g_pos[i * 8 + p] * invT;
      { float m = fmaxf(a, m1); loss += m + logf(expf(a - m) + s1 * expf(m1 - m)) - a; }
      { float m = fmaxf(a, m2); loss += m + logf(expf(a - m) + s2 * expf(m2 - m)) - a; }
    }
  }
  g_rowloss[i] = loss;
  g_rowvalid[i] = valid;
}

__global__ __launch_bounds__(256) void k_final(float* out) {
  __shared__ float sl[256];
  __shared__ int sc[256];
  int t = threadIdx.x;
  float l = 0.0f; int c = 0;
  for (int i = t; i < NROW; i += 256) { l += g_rowloss[i]; c += g_rowvalid[i]; }
  sl[t] = l; sc[t] = c;
  __syncthreads();
  for (int s = 128; s > 0; s >>= 1) {
    if (t < s) { sl[t] += sl[t + s]; sc[t] += sc[t + s]; }
    __syncthreads();
  }
  if (t == 0) out[0] = (sc[0] > 0) ? sl[0] / ((float)sc[0] * 16.0f) : 0.0f;
}

// ---------------- launch ----------------------------------------------------
extern "C" void kernel_launch(void* const* d_in, const int* in_sizes, int n_in,
                              void* d_out, int out_size, void* d_ws, size_t ws_size,
                              hipStream_t stream) {
  const float* f          = (const float*)d_in[0];
  const float* W          = (const float*)d_in[1];
  const float* b          = (const float*)d_in[2];
  const float* Bank       = (const float*)d_in[3];
  const float* bank_flag  = (const float*)d_in[4];
  const int*   label      = (const int*)d_in[5];
  const long long* in_idx = (const long long*)d_in[6];
  const int*   label_all  = (const int*)d_in[7];
  float* out = (float*)d_out;

  hipLaunchKernelGGL(k_owner_init,    dim3(MEMN / 256), dim3(256), 0, stream);
  hipLaunchKernelGGL(k_owner_scatter, dim3(NROW / 256), dim3(256), 0, stream, in_idx);
  hipLaunchKernelGGL(k_meta,          dim3(MEMN / 256), dim3(256), 0, stream, bank_flag, label_all);
  hipLaunchKernelGGL(k_fn,            dim3(NROW),       dim3(256), 0, stream, f, W, b);
  hipLaunchKernelGGL(k_bank2,         dim3(MEMN / 4),   dim3(256), 0, stream, Bank);
  hipLaunchKernelGGL(k_gemm_rand,     dim3(4096),       dim3(256), 0, stream);
  hipLaunchKernelGGL(k_scan,          dim3(NROW * 8),   dim3(256), 0, stream, label);
  hipLaunchKernelGGL(k_select,        dim3(NROW),       dim3(192), 0, stream, label);
  hipLaunchKernelGGL(k_loss,          dim3(NROW / 256), dim3(256), 0, stream, label);
  hipLaunchKernelGGL(k_final,         dim3(1),          dim3(256), 0, stream, out);
}